// Round 8
// baseline (91.668 us; speedup 1.0000x reference)
//
#include <hip/hip_runtime.h>
#include <math.h>

// Barrier_Net: deep-sets net + barrier + global max-rescale.
// R6 WIN: removed same-address atomic storm (-9us). R7 WIN: fused per-row
// pipeline, 2 dispatches (-5.5us). Remaining gap vs VALU model (~3x) with
// NO saturated pipe (VALUBusy ~33%, Occ ~20%) => latency/critical-path
// bound. R8: halve per-wave critical path (2 rows/block, wave-pair splits
// the 66-neighbor loop into 33+33; phases 2-4 halve their FMA depth) and
// double occupancy (8 blocks/CU via __launch_bounds__(256,8), 32 waves/CU).

#define NBLK 2048   // 2 rows/block, 4096 rows

__global__ __launch_bounds__(256, 8) void bn_row(
    const float* __restrict__ x,
    const float* __restrict__ w1,  const float* __restrict__ b1,
    const float* __restrict__ w2,  const float* __restrict__ b2,
    const float* __restrict__ rw1, const float* __restrict__ rb1,
    const float* __restrict__ rw2, const float* __restrict__ rb2,
    float* __restrict__ out, float* __restrict__ blkmax)
{
    __shared__ __align__(16) float sx[2][268];    // per-row x buffer
    __shared__ __align__(16) float sHp[4][264];   // per-wave partial H
    __shared__ __align__(16) float sH[2][264];    // folded H per row
    __shared__ float sXp[4][2][68];               // [wave][row][o] partials
    __shared__ __align__(16) float sX[2][68];     // folded phi-sum per row
    __shared__ float sP4[4][2][2];                // [wave][row][c]
    __shared__ float sbar[2][2];
    __shared__ float sa[4];

    const int tid = threadIdx.x;
    const int ln  = tid & 63;
    const int wv  = tid >> 6;
    const int p   = wv & 1;        // n-half within the row (0: n<33, 1: n>=33)
    const int rp  = wv >> 1;       // row within block
    const int r0  = blockIdx.x * 2;
    const int row = r0 + rp;
    const float4* __restrict__ x4 = (const float4*)(x + (size_t)row * 264);

    // ---- stage x: wave p=0 loads n=0..63; wave p=1 loads n=ln+2 (covers 64,65
    // and holds the barrier data in registers) ----
    float4 pv;                     // only valid for p==1 waves
    if (p == 0) {
        float4 xr = x4[ln];
        ((float4*)sx[rp])[ln] = xr;
    } else {
        pv = x4[ln + 2];
        if (ln >= 62) ((float4*)sx[rp])[ln + 2] = pv;   // slots 64, 65
    }

    // per-lane weights: lane ln owns hidden units 4ln..4ln+3
    float4 w1r0 = ((const float4*)(w1      ))[ln];
    float4 w1r1 = ((const float4*)(w1 + 256))[ln];
    float4 w1r2 = ((const float4*)(w1 + 512))[ln];
    float4 w1r3 = ((const float4*)(w1 + 768))[ln];
    float4 b1r  = ((const float4*)b1)[ln];
    __syncthreads();

    // ---- phase 1 (split): wave sums its 33-neighbor half ----
    float a0 = 0.f, a1 = 0.f, a2 = 0.f, a3 = 0.f;
    {
        const int nbeg = p * 33;
        #pragma unroll 3
        for (int j = 0; j < 33; j++) {
            float4 xv = ((const float4*)sx[rp])[nbeg + j];
            float h0 = b1r.x, h1 = b1r.y, h2 = b1r.z, h3 = b1r.w;
            h0 = fmaf(xv.x, w1r0.x, h0); h1 = fmaf(xv.x, w1r0.y, h1);
            h2 = fmaf(xv.x, w1r0.z, h2); h3 = fmaf(xv.x, w1r0.w, h3);
            h0 = fmaf(xv.y, w1r1.x, h0); h1 = fmaf(xv.y, w1r1.y, h1);
            h2 = fmaf(xv.y, w1r1.z, h2); h3 = fmaf(xv.y, w1r1.w, h3);
            h0 = fmaf(xv.z, w1r2.x, h0); h1 = fmaf(xv.z, w1r2.y, h1);
            h2 = fmaf(xv.z, w1r2.z, h2); h3 = fmaf(xv.z, w1r2.w, h3);
            h0 = fmaf(xv.w, w1r3.x, h0); h1 = fmaf(xv.w, w1r3.y, h1);
            h2 = fmaf(xv.w, w1r3.z, h2); h3 = fmaf(xv.w, w1r3.w, h3);
            a0 += fmaxf(h0, 0.f); a1 += fmaxf(h1, 0.f);
            a2 += fmaxf(h2, 0.f); a3 += fmaxf(h3, 0.f);
        }
    }
    ((float4*)sHp[wv])[ln] = make_float4(a0, a1, a2, a3);

    // barrier term (p==1 waves hold pv: lane ln <-> neighbor ln+2, all 64)
    if (p == 1) {
        float px = pv.x, py = pv.y;
        float d  = sqrtf(px * px + py * py);
        float t  = d - 0.15f;
        float inv = 1.0f / (t * t);
        float bx = -px * inv, by = -py * inv;
        #pragma unroll
        for (int m = 32; m >= 1; m >>= 1) {
            bx += __shfl_xor(bx, m);
            by += __shfl_xor(by, m);
        }
        if (ln == 0) { sbar[rp][0] = bx; sbar[rp][1] = by; }
    }
    __syncthreads();

    // fold the two n-half partials -> H per row (512 values, 2 per thread)
    for (int t = tid; t < 512; t += 256) {
        int r = t >> 8, k = t & 255;
        sH[r][k] = sHp[2 * r][k] + sHp[2 * r + 1][k];
    }
    __syncthreads();

    // ---- phase 2: X[r][o] = sum_k H[r][k] w2[k][o] + 66 b2[o] ----
    // wave wv owns k-quarter [64wv, 64wv+64); lane = o; both rows.
    {
        float xp0 = 0.f, xp1 = 0.f;
        const float* w2q = w2 + (wv << 12);
        #pragma unroll 4
        for (int i = 0; i < 16; i++) {
            int kb = (wv << 4) + i;
            float4 h0 = ((const float4*)sH[0])[kb];   // uniform broadcast
            float4 h1 = ((const float4*)sH[1])[kb];
            float wk0 = w2q[(((i << 2) + 0) << 6) + ln];
            float wk1 = w2q[(((i << 2) + 1) << 6) + ln];
            float wk2 = w2q[(((i << 2) + 2) << 6) + ln];
            float wk3 = w2q[(((i << 2) + 3) << 6) + ln];
            xp0 = fmaf(h0.x, wk0, xp0); xp1 = fmaf(h1.x, wk0, xp1);
            xp0 = fmaf(h0.y, wk1, xp0); xp1 = fmaf(h1.y, wk1, xp1);
            xp0 = fmaf(h0.z, wk2, xp0); xp1 = fmaf(h1.z, wk2, xp1);
            xp0 = fmaf(h0.w, wk3, xp0); xp1 = fmaf(h1.w, wk3, xp1);
        }
        sXp[wv][0][ln] = xp0; sXp[wv][1][ln] = xp1;
    }
    __syncthreads();

    // fold k-quarter partials -> X (waves 0,1 handle rows 0,1)
    if (wv < 2) {
        sX[wv][ln] = sXp[0][wv][ln] + sXp[1][wv][ln]
                   + sXp[2][wv][ln] + sXp[3][wv][ln] + 66.0f * b2[ln];
    }
    __syncthreads();

    // ---- phase 3: h2[r][h] = relu(sum_o X[r][o] rw1[o][h] + rb1[h]), h=tid ----
    float c0, c1;
    c0 = c1 = rb1[tid];
    #pragma unroll 4
    for (int i = 0; i < 16; i++) {
        float4 X0 = ((const float4*)sX[0])[i];
        float4 X1 = ((const float4*)sX[1])[i];
        float q0 = rw1[(((i << 2) + 0) << 8) + tid];
        float q1 = rw1[(((i << 2) + 1) << 8) + tid];
        float q2 = rw1[(((i << 2) + 2) << 8) + tid];
        float q3 = rw1[(((i << 2) + 3) << 8) + tid];
        c0 = fmaf(X0.x, q0, c0); c1 = fmaf(X1.x, q0, c1);
        c0 = fmaf(X0.y, q1, c0); c1 = fmaf(X1.y, q1, c1);
        c0 = fmaf(X0.z, q2, c0); c1 = fmaf(X1.z, q2, c1);
        c0 = fmaf(X0.w, q3, c0); c1 = fmaf(X1.w, q3, c1);
    }
    c0 = fmaxf(c0, 0.f); c1 = fmaxf(c1, 0.f);

    // ---- phase 4: pre[r][c] = sum_h h2[r][h] rw2[h][c]; butterfly over h ----
    {
        float2 r2v = ((const float2*)rw2)[tid];
        float p00 = c0 * r2v.x, p01 = c0 * r2v.y;
        float p10 = c1 * r2v.x, p11 = c1 * r2v.y;
        #pragma unroll
        for (int m = 32; m >= 1; m >>= 1) {
            p00 += __shfl_xor(p00, m); p01 += __shfl_xor(p01, m);
            p10 += __shfl_xor(p10, m); p11 += __shfl_xor(p11, m);
        }
        if (ln == 0) {
            sP4[wv][0][0] = p00; sP4[wv][0][1] = p01;
            sP4[wv][1][0] = p10; sP4[wv][1][1] = p11;
        }
    }
    __syncthreads();

    if (tid < 4) {
        int r = tid >> 1, c = tid & 1;
        float pre = sP4[0][r][c] + sP4[1][r][c] + sP4[2][r][c] + sP4[3][r][c]
                  + rb2[c];
        float a = 2.0f * tanhf(pre) + sbar[r][c];
        out[r0 * 2 + tid] = a;
        sa[tid] = a;
    }
    __syncthreads();
    // No global atomic: block max -> distinct slot (plain store).
    if (tid == 0) {
        float m = fmaxf(fmaxf(sa[0], sa[1]), fmaxf(sa[2], sa[3]));
        blkmax[blockIdx.x] = m;
    }
}

// ---- K2: reduce 2048 block maxima (L2-hot) + conditional rescale ----
__global__ __launch_bounds__(256) void bn_scale(
    float* __restrict__ out, const float* __restrict__ blkmax)
{
    __shared__ float sm[4];
    const int tid = threadIdx.x;
    const int ln  = tid & 63;
    const int wv  = tid >> 6;

    float m = blkmax[tid];
    #pragma unroll
    for (int j = 1; j < 8; j++) m = fmaxf(m, blkmax[tid + 256 * j]);
    #pragma unroll
    for (int s = 32; s >= 1; s >>= 1) m = fmaxf(m, __shfl_xor(m, s));
    if (ln == 0) sm[wv] = m;
    __syncthreads();
    float amax = fmaxf(fmaxf(sm[0], sm[1]), fmaxf(sm[2], sm[3]));

    float scale = 2.0f / amax;
    int i = blockIdx.x * 256 + tid;
    float a = out[i];
    out[i] = (scale < 1.0f) ? a * scale : a;
}

extern "C" void kernel_launch(void* const* d_in, const int* in_sizes, int n_in,
                              void* d_out, int out_size, void* d_ws, size_t ws_size,
                              hipStream_t stream) {
    const float* x   = (const float*)d_in[0];
    const float* w1  = (const float*)d_in[1];
    const float* b1  = (const float*)d_in[2];
    const float* w2  = (const float*)d_in[3];
    const float* b2  = (const float*)d_in[4];
    const float* rw1 = (const float*)d_in[5];
    const float* rb1 = (const float*)d_in[6];
    const float* rw2 = (const float*)d_in[7];
    const float* rb2 = (const float*)d_in[8];
    float* out = (float*)d_out;
    float* blkmax = (float*)d_ws;   // 2048 distinct slots, no init needed

    bn_row<<<NBLK, 256, 0, stream>>>(x, w1, b1, w2, b2, rw1, rb1, rw2, rb2,
                                     out, blkmax);
    bn_scale<<<8192 / 256, 256, 0, stream>>>(out, blkmax);
}